// Round 1
// baseline (845.765 us; speedup 1.0000x reference)
//
#include <hip/hip_runtime.h>
#include <hip/hip_bf16.h>

typedef float f32x16 __attribute__((ext_vector_type(16)));
typedef float f32x4  __attribute__((ext_vector_type(4)));
typedef __bf16 bf16x8 __attribute__((ext_vector_type(8)));

#define PERM_HI 0x07060302u   // pick bytes[3:2] of (even,odd) -> (lo16=hi(even), hi16=hi(odd))
#define PERM_LO 0x05040100u   // pick bytes[1:0]

__device__ __forceinline__ unsigned prm(unsigned a, unsigned b, unsigned s) {
  return __builtin_amdgcn_perm(a, b, s);
}

// LDS layout: row-major [64][256] f32, with a per-row rotation *within each
// 32-col block*: conflict-frees strided column reads, keeps float4 runs intact,
// and keeps each 32-col slab physically private to its owning wave in phase D.
__device__ __forceinline__ int lidx(int row, int kj) {
  return row * 256 + (kj & ~31) + ((kj + ((row & 7) << 2)) & 31);
}

// fp32 -> packed (bf16_hi << 16) | bf16_lo  (truncation split; lo captures residual)
__device__ __forceinline__ unsigned packsplit(float v) {
  unsigned bits = __float_as_uint(v);
  unsigned hi = bits & 0xFFFF0000u;
  float lof = v - __uint_as_float(hi);
  return hi | (__float_as_uint(lof) >> 16);
}

// ---------------- Gauss-Jordan inverse of A (16x16), 4 lanes per matrix -----
// Lane (q = lane&3) owns rows {q, 4+q, 8+q, 12+q}. Column-op elimination:
// at pivot p broadcast row p (A-row, pre-update) from owner lane via ds_swizzle.
// Register x[r][l]: A-row before its pivot, V=A^{-1}-row after (element-exact reuse).
template <int P>
struct GJStep {
  static __device__ __forceinline__ void run(float (&x)[4][16], int q) {
    constexpr int RP = P >> 2;
    constexpr int QP = P & 3;
    float rp[16];
#pragma unroll
    for (int l = 0; l < 16; ++l)
      rp[l] = __int_as_float(
          __builtin_amdgcn_ds_swizzle(__float_as_int(x[RP][l]), 0x1C | (QP << 5)));
    float ap = rp[P];
    float r0 = __builtin_amdgcn_rcpf(ap);
    float inv = r0 * (2.0f - ap * r0);   // 1 Newton step -> ~fp32-exact
#pragma unroll
    for (int r = 0; r < 4; ++r) {
      if (r == RP && q == QP) {          // this lane owns pivot row: rebirth A->V
#pragma unroll
        for (int l = 0; l < 16; ++l) x[r][l] = (l == P) ? inv : (-rp[l] * inv);
      } else {
        float gm = x[r][P] * inv;
#pragma unroll
        for (int l = 0; l < 16; ++l)
          if (l != P) x[r][l] = fmaf(-rp[l], gm, x[r][l]);
        x[r][P] = gm;
      }
    }
    GJStep<P + 1>::run(x, q);
  }
};
template <>
struct GJStep<16> {
  static __device__ __forceinline__ void run(float (&)[4][16], int) {}
};

// ---------------- weight prep: split/reorder weight into MFMA A-fragments ---
// arr0: w1 (scol 16+s), 32x32x16 layout; arr1: w0 (scol s), 32x32x16;
// arr2: w2 (scol 32+s), 16x16x32 layout. Each array: 65536 hi + 65536 lo u16.
extern "C" __global__ void kW_prep(const float* __restrict__ w,
                                   unsigned short* __restrict__ o) {
  int gid = blockIdx.x * 256 + threadIdx.x;   // 0..196607
  int arr = gid >> 16;
  int r = gid & 65535;
  int s = r >> 12;
  int tcb = (r >> 9) & 7;
  int l = (r >> 3) & 63;
  int e = r & 7;
  int c, i, sc;
  if (arr < 2) {
    int t = tcb >> 1, cb = tcb & 1;
    c = cb * 32 + (l & 31);
    i = t * 16 + ((l >> 5) << 3) + e;
    sc = (arr == 0) ? (16 + s) : s;
  } else {
    int t = tcb >> 2, cb = tcb & 3;
    c = cb * 16 + (l & 15);
    i = t * 32 + ((l >> 4) << 3) + e;
    sc = 32 + s;
  }
  float v = w[i * 3072 + sc * 64 + c];
  unsigned bits = __float_as_uint(v);
  unsigned hi = bits & 0xFFFF0000u;
  float lof = v - __uint_as_float(hi);
  o[arr * 131072 + r] = (unsigned short)(bits >> 16);
  o[arr * 131072 + 65536 + r] = (unsigned short)(__float_as_uint(lof) >> 16);
}

// ---------------- out1: Cayley -> mix (MFMA bf16x3) -> Cayley, fused --------
extern "C" __global__ void __launch_bounds__(256, 2)
k1_out1(const float* __restrict__ core1, const unsigned short* __restrict__ wh,
        const unsigned short* __restrict__ wl, float* __restrict__ out1) {
  __shared__ float lds_f[16384];               // 64 KB, reused 3x
  unsigned* lds_u = (unsigned*)lds_f;

  const int tid = threadIdx.x;
  const int wv = tid >> 6;
  const int ln = tid & 63;
  const int q = ln & 3;
  const int mi = wv * 16 + (ln >> 2);          // matrix owned by this 4-lane group

  // map so the s / s+1 halves of each 128B line go to the same XCD (idx, idx+8)
  const int u = blockIdx.x & 15;
  const int b = blockIdx.x >> 4;
  const int s = ((u & 7) << 1) | (u >> 3);

  // Phase A: stage core1[:, b, :, s, :] -> LDS  (64 matrices of 16x16)
  const float* src = core1 + b * 4096 + s * 16;
#pragma unroll
  for (int it = 0; it < 16; ++it) {
    int f = tid + it * 256;
    int i = f >> 6;
    int k = (f >> 2) & 15;
    int q4 = (f & 3) << 2;
    float4 v = *(const float4*)(src + i * 1048576 + k * 256 + q4);
    *(float4*)&lds_f[lidx(i, k * 16 + q4)] = v;
  }
  __syncthreads();

  float x[4][16];

  // Phase B: GJ-1 init  A = I + (M - M^T); rows 4r+q of matrix mi
#pragma unroll
  for (int r = 0; r < 4; ++r) {
    int row = 4 * r + q;
    float rowv[16];
#pragma unroll
    for (int c4 = 0; c4 < 4; ++c4) {
      float4 rv = *(const float4*)&lds_f[lidx(mi, row * 16 + c4 * 4)];
      rowv[4 * c4 + 0] = rv.x; rowv[4 * c4 + 1] = rv.y;
      rowv[4 * c4 + 2] = rv.z; rowv[4 * c4 + 3] = rv.w;
    }
#pragma unroll
    for (int l = 0; l < 16; ++l) {
      float mc = lds_f[lidx(mi, l * 16 + row)];
      x[r][l] = rowv[l] - mc + ((l == row) ? 1.0f : 0.0f);
    }
  }
  GJStep<0>::run(x, q);

  // Phase C: Q1 = 2V - I, packed bf16 hi/lo, overwrite own matrix region
#pragma unroll
  for (int r = 0; r < 4; ++r) {
    int row = 4 * r + q;
    unsigned wb[16];
#pragma unroll
    for (int l = 0; l < 16; ++l) {
      float qv = 2.0f * x[r][l] - ((l == row) ? 1.0f : 0.0f);
      wb[l] = packsplit(qv);
    }
#pragma unroll
    for (int c4 = 0; c4 < 4; ++c4) {
      uint4 U;
      U.x = wb[4 * c4]; U.y = wb[4 * c4 + 1]; U.z = wb[4 * c4 + 2]; U.w = wb[4 * c4 + 3];
      *(uint4*)&lds_u[lidx(mi, row * 16 + c4 * 4)] = U;
    }
  }
  __syncthreads();

  // Phase D: m[c][kj] = sum_i w1[i,s,c] * Q1_i[kj]  (MFMA 32x32x16, 3-term bf16)
  // wave wv owns column slabs kjb = wv and 4+wv; writes m over the slab it read.
  {
    uint4 AH[2][4], AL[2][4];
#pragma unroll
    for (int cb = 0; cb < 2; ++cb)
#pragma unroll
      for (int t = 0; t < 4; ++t) {
        int off = (((s * 4 + t) * 2 + cb) * 64 + ln) * 8;
        AH[cb][t] = *(const uint4*)(wh + off);
        AL[cb][t] = *(const uint4*)(wl + off);
      }
    const int hb = (ln >> 5) << 3;
#pragma unroll
    for (int ch = 0; ch < 2; ++ch) {
      int kjp = (ch * 4 + wv) * 32 + (ln & 31);
      f32x16 acc0, acc1;
#pragma unroll
      for (int z = 0; z < 16; ++z) { acc0[z] = 0.0f; acc1[z] = 0.0f; }
#pragma unroll
      for (int t = 0; t < 4; ++t) {
        unsigned w32[8];
#pragma unroll
        for (int e = 0; e < 8; ++e)
          w32[e] = lds_u[lidx(t * 16 + hb + e, kjp)];
        uint4 BH, BL;
        BH.x = prm(w32[1], w32[0], PERM_HI); BH.y = prm(w32[3], w32[2], PERM_HI);
        BH.z = prm(w32[5], w32[4], PERM_HI); BH.w = prm(w32[7], w32[6], PERM_HI);
        BL.x = prm(w32[1], w32[0], PERM_LO); BL.y = prm(w32[3], w32[2], PERM_LO);
        BL.z = prm(w32[5], w32[4], PERM_LO); BL.w = prm(w32[7], w32[6], PERM_LO);
        bf16x8 bhv = __builtin_bit_cast(bf16x8, BH);
        bf16x8 blv = __builtin_bit_cast(bf16x8, BL);
        bf16x8 a0h = __builtin_bit_cast(bf16x8, AH[0][t]);
        bf16x8 a0l = __builtin_bit_cast(bf16x8, AL[0][t]);
        bf16x8 a1h = __builtin_bit_cast(bf16x8, AH[1][t]);
        bf16x8 a1l = __builtin_bit_cast(bf16x8, AL[1][t]);
        acc0 = __builtin_amdgcn_mfma_f32_32x32x16_bf16(a0h, bhv, acc0, 0, 0, 0);
        acc0 = __builtin_amdgcn_mfma_f32_32x32x16_bf16(a0h, blv, acc0, 0, 0, 0);
        acc0 = __builtin_amdgcn_mfma_f32_32x32x16_bf16(a0l, bhv, acc0, 0, 0, 0);
        acc1 = __builtin_amdgcn_mfma_f32_32x32x16_bf16(a1h, bhv, acc1, 0, 0, 0);
        acc1 = __builtin_amdgcn_mfma_f32_32x32x16_bf16(a1h, blv, acc1, 0, 0, 0);
        acc1 = __builtin_amdgcn_mfma_f32_32x32x16_bf16(a1l, bhv, acc1, 0, 0, 0);
      }
#pragma unroll
      for (int rg = 0; rg < 16; ++rg) {
        int row32 = (rg & 3) + ((rg >> 2) << 3) + ((ln >> 5) << 2);
        lds_f[lidx(row32, kjp)] = acc0[rg];
        lds_f[lidx(32 + row32, kjp)] = acc1[rg];
      }
    }
  }
  __syncthreads();

  // Phase E: GJ-2 init from m (matrix index = output channel c = mi)
#pragma unroll
  for (int r = 0; r < 4; ++r) {
    int row = 4 * r + q;
    float rowv[16];
#pragma unroll
    for (int c4 = 0; c4 < 4; ++c4) {
      float4 rv = *(const float4*)&lds_f[lidx(mi, row * 16 + c4 * 4)];
      rowv[4 * c4 + 0] = rv.x; rowv[4 * c4 + 1] = rv.y;
      rowv[4 * c4 + 2] = rv.z; rowv[4 * c4 + 3] = rv.w;
    }
#pragma unroll
    for (int l = 0; l < 16; ++l) {
      float mc = lds_f[lidx(mi, l * 16 + row)];
      x[r][l] = rowv[l] - mc + ((l == row) ? 1.0f : 0.0f);
    }
  }
  GJStep<0>::run(x, q);

  // Phase F: out1 rows = 2V - I, coalesced 64B stores
  float* dst = out1 + (size_t)mi * 1048576 + b * 4096 + s * 16;
#pragma unroll
  for (int r = 0; r < 4; ++r) {
    int row = 4 * r + q;
    float ov[16];
#pragma unroll
    for (int l = 0; l < 16; ++l)
      ov[l] = 2.0f * x[r][l] - ((l == row) ? 1.0f : 0.0f);
#pragma unroll
    for (int c4 = 0; c4 < 4; ++c4) {
      float4 o4;
      o4.x = ov[4 * c4]; o4.y = ov[4 * c4 + 1]; o4.z = ov[4 * c4 + 2]; o4.w = ov[4 * c4 + 3];
      *(float4*)(dst + row * 256 + c4 * 4) = o4;
    }
  }
}

// ---------------- out0: plain mix via MFMA 32x32x16 (B direct from global) --
extern "C" __global__ void __launch_bounds__(256)
k0_out0(const float* __restrict__ core0, const unsigned short* __restrict__ wh,
        const unsigned short* __restrict__ wl, float* __restrict__ out0) {
  const int tid = threadIdx.x;
  const int wv = tid >> 6;
  const int ln = tid & 63;
  const int u = blockIdx.x & 15;
  const int bt = blockIdx.x >> 4;
  const int s = ((u & 7) << 1) | (u >> 3);
  const int col = (bt * 4 + wv) * 32 + (ln & 31);   // bj in [0,4096)
  const int b = col >> 4, j = col & 15;
  const int hb = (ln >> 5) << 3;

  uint4 AH[2][4], AL[2][4];
#pragma unroll
  for (int cb = 0; cb < 2; ++cb)
#pragma unroll
    for (int t = 0; t < 4; ++t) {
      int off = (((s * 4 + t) * 2 + cb) * 64 + ln) * 8;
      AH[cb][t] = *(const uint4*)(wh + off);
      AL[cb][t] = *(const uint4*)(wl + off);
    }
  f32x16 acc0, acc1;
#pragma unroll
  for (int z = 0; z < 16; ++z) { acc0[z] = 0.0f; acc1[z] = 0.0f; }

  const float* bp = core0 + b * 256 + s * 16 + j;
#pragma unroll
  for (int t = 0; t < 4; ++t) {
    float v[8]; unsigned rb[8], lb[8];
#pragma unroll
    for (int e = 0; e < 8; ++e) {
      int i = t * 16 + hb + e;
      v[e] = bp[i * 65536];
      rb[e] = __float_as_uint(v[e]);
    }
#pragma unroll
    for (int e = 0; e < 8; ++e) {
      float lof = v[e] - __uint_as_float(rb[e] & 0xFFFF0000u);
      lb[e] = __float_as_uint(lof);
    }
    uint4 BH, BL;
    BH.x = prm(rb[1], rb[0], PERM_HI); BH.y = prm(rb[3], rb[2], PERM_HI);
    BH.z = prm(rb[5], rb[4], PERM_HI); BH.w = prm(rb[7], rb[6], PERM_HI);
    BL.x = prm(lb[1], lb[0], PERM_HI); BL.y = prm(lb[3], lb[2], PERM_HI);
    BL.z = prm(lb[5], lb[4], PERM_HI); BL.w = prm(lb[7], lb[6], PERM_HI);
    bf16x8 bhv = __builtin_bit_cast(bf16x8, BH);
    bf16x8 blv = __builtin_bit_cast(bf16x8, BL);
    bf16x8 a0h = __builtin_bit_cast(bf16x8, AH[0][t]);
    bf16x8 a0l = __builtin_bit_cast(bf16x8, AL[0][t]);
    bf16x8 a1h = __builtin_bit_cast(bf16x8, AH[1][t]);
    bf16x8 a1l = __builtin_bit_cast(bf16x8, AL[1][t]);
    acc0 = __builtin_amdgcn_mfma_f32_32x32x16_bf16(a0h, bhv, acc0, 0, 0, 0);
    acc0 = __builtin_amdgcn_mfma_f32_32x32x16_bf16(a0h, blv, acc0, 0, 0, 0);
    acc0 = __builtin_amdgcn_mfma_f32_32x32x16_bf16(a0l, bhv, acc0, 0, 0, 0);
    acc1 = __builtin_amdgcn_mfma_f32_32x32x16_bf16(a1h, bhv, acc1, 0, 0, 0);
    acc1 = __builtin_amdgcn_mfma_f32_32x32x16_bf16(a1h, blv, acc1, 0, 0, 0);
    acc1 = __builtin_amdgcn_mfma_f32_32x32x16_bf16(a1l, bhv, acc1, 0, 0, 0);
  }
#pragma unroll
  for (int rg = 0; rg < 16; ++rg) {
    int row32 = (rg & 3) + ((rg >> 2) << 3) + ((ln >> 5) << 2);
    out0[row32 * 65536 + b * 256 + s * 16 + j] = acc0[rg];
    out0[(32 + row32) * 65536 + b * 256 + s * 16 + j] = acc1[rg];
  }
}

// ---------------- out2: mix via MFMA 16x16x32; all 16 s of a line in-block --
extern "C" __global__ void __launch_bounds__(256)
k2_out2(const float* __restrict__ core2, const unsigned short* __restrict__ wh,
        const unsigned short* __restrict__ wl, float* __restrict__ out2) {
  const int tid = threadIdx.x;
  const int wv = tid >> 6;
  const int ln = tid & 63;
  const int b = blockIdx.x >> 1;
  const int sh = blockIdx.x & 1;
  const int kc = ln & 15, h = ln >> 4;

  const float* bp = core2 + b * 256 + kc * 16;
#pragma unroll
  for (int sl = 0; sl < 2; ++sl) {
    int s = sh * 8 + wv * 2 + sl;
    uint4 AH[4][2], AL[4][2];
#pragma unroll
    for (int cb = 0; cb < 4; ++cb)
#pragma unroll
      for (int t = 0; t < 2; ++t) {
        int off = (((s * 2 + t) * 4 + cb) * 64 + ln) * 8;
        AH[cb][t] = *(const uint4*)(wh + off);
        AL[cb][t] = *(const uint4*)(wl + off);
      }
    f32x4 acc[4];
#pragma unroll
    for (int cb = 0; cb < 4; ++cb)
#pragma unroll
      for (int z = 0; z < 4; ++z) acc[cb][z] = 0.0f;
#pragma unroll
    for (int t = 0; t < 2; ++t) {
      float v[8]; unsigned rb[8], lb[8];
#pragma unroll
      for (int e = 0; e < 8; ++e) {
        int i = t * 32 + h * 8 + e;
        v[e] = bp[i * 65536 + s];
        rb[e] = __float_as_uint(v[e]);
      }
#pragma unroll
      for (int e = 0; e < 8; ++e) {
        float lof = v[e] - __uint_as_float(rb[e] & 0xFFFF0000u);
        lb[e] = __float_as_uint(lof);
      }
      uint4 BH, BL;
      BH.x = prm(rb[1], rb[0], PERM_HI); BH.y = prm(rb[3], rb[2], PERM_HI);
      BH.z = prm(rb[5], rb[4], PERM_HI); BH.w = prm(rb[7], rb[6], PERM_HI);
      BL.x = prm(lb[1], lb[0], PERM_HI); BL.y = prm(lb[3], lb[2], PERM_HI);
      BL.z = prm(lb[5], lb[4], PERM_HI); BL.w = prm(lb[7], lb[6], PERM_HI);
      bf16x8 bhv = __builtin_bit_cast(bf16x8, BH);
      bf16x8 blv = __builtin_bit_cast(bf16x8, BL);
#pragma unroll
      for (int cb = 0; cb < 4; ++cb) {
        bf16x8 ach = __builtin_bit_cast(bf16x8, AH[cb][t]);
        bf16x8 acl = __builtin_bit_cast(bf16x8, AL[cb][t]);
        acc[cb] = __builtin_amdgcn_mfma_f32_16x16x32_bf16(ach, bhv, acc[cb], 0, 0, 0);
        acc[cb] = __builtin_amdgcn_mfma_f32_16x16x32_bf16(ach, blv, acc[cb], 0, 0, 0);
        acc[cb] = __builtin_amdgcn_mfma_f32_16x16x32_bf16(acl, bhv, acc[cb], 0, 0, 0);
      }
    }
#pragma unroll
    for (int cb = 0; cb < 4; ++cb)
#pragma unroll
      for (int rg = 0; rg < 4; ++rg) {
        int c = cb * 16 + h * 4 + rg;
        out2[c * 65536 + b * 256 + kc * 16 + s] = acc[cb][rg];
      }
  }
}

extern "C" void kernel_launch(void* const* d_in, const int* in_sizes, int n_in,
                              void* d_out, int out_size, void* d_ws, size_t ws_size,
                              hipStream_t stream) {
  (void)in_sizes; (void)n_in; (void)out_size; (void)ws_size;
  const float* core0 = (const float*)d_in[0];
  const float* core1 = (const float*)d_in[1];
  const float* core2 = (const float*)d_in[2];
  const float* weight = (const float*)d_in[3];
  float* out = (float*)d_out;
  unsigned short* wsp = (unsigned short*)d_ws;

  // out layout (f32): out0 [0, 4194304), out1 [4194304, 71303168), out2 [71303168, 75497472)
  kW_prep<<<dim3(768), dim3(256), 0, stream>>>(weight, wsp);
  k1_out1<<<dim3(4096), dim3(256), 0, stream>>>(core1, wsp + 0, wsp + 65536,
                                                out + 4194304);
  k0_out0<<<dim3(512), dim3(256), 0, stream>>>(core0, wsp + 131072, wsp + 196608, out);
  k2_out2<<<dim3(512), dim3(256), 0, stream>>>(core2, wsp + 262144, wsp + 327680,
                                               out + 71303168);
}